// Round 2
// baseline (164.403 us; speedup 1.0000x reference)
//
#include <hip/hip_runtime.h>
#include <hip/hip_fp16.h>
#include <math.h>

// Problem dims (fixed)
#define B     4096
#define NIN   512
#define L     16
#define N     512
#define K     32
#define NOUT  256
#define HID   (L * N)          // 8192
#define TOTAL (NIN + L * N)    // 8704
#define BROWS 4                // batch rows per block
#define BLOCK 512              // one neuron per thread per layer

typedef __attribute__((ext_vector_type(2))) _Float16 hv2;         // 4 B: 2 fp16
typedef __attribute__((ext_vector_type(8))) _Float16 h8;          // 16 B: 8 packed fp16 weights
typedef __attribute__((ext_vector_type(8))) unsigned short u16x8; // 16 B: 8 packed u16 indices

// 8 B LDS entry: 4 batch rows of one column as two fp16 pairs
struct alignas(8) hh { hv2 lo, hi; };

__device__ __forceinline__ float sigmoidf_fast(float z) {
    return 1.0f / (1.0f + __expf(-z));
}

// ---- repack with BANK BALANCING (workspace footprint UNCHANGED vs the
// proven 1.08 MB layout — u16 element indices, fp16 weights):
//  * per neuron, counting-sort the 32 (idx,w) pairs by bank-pair key
//    (idx & 15), then rotate slots by (neuron % 32). At gather slot j the
//    lanes of a half-wave read 32 distinct sorted positions -> bank-pairs
//    near-equidistributed (~4 lanes/bank, the ds_read_b64 wave64 floor)
//    instead of multinomial-random (~8-10 way).
//  Dot product is permutation-invariant, so this is numerically free.
__global__ void repack_kernel(const float* __restrict__ W,
                              const int*   __restrict__ idx,
                              const float* __restrict__ W_out,
                              const int*   __restrict__ idx_out,
                              _Float16* __restrict__ wh,
                              unsigned short* __restrict__ i16,
                              _Float16* __restrict__ who,
                              unsigned short* __restrict__ io16)
{
    const int n = blockIdx.x * 256 + threadIdx.x;
    const int* ip; const float* wp; _Float16* wo; unsigned short* io;
    if (n < HID) {
        ip = idx + (size_t)n * K;      wp = W + (size_t)n * K;
        wo = wh + (size_t)n * K;       io = i16 + (size_t)n * K;
    } else if (n < HID + NOUT) {
        const int m = n - HID;
        ip = idx_out + (size_t)m * K;  wp = W_out + (size_t)m * K;
        wo = who + (size_t)m * K;      io = io16 + (size_t)m * K;
    } else {
        return;
    }
    const int rot = n & 31;   // HID%32==0, so this is also (n-HID)&31 for outputs

    int ci[K]; float cw[K];
#pragma unroll
    for (int j = 0; j < K; ++j) { ci[j] = ip[j]; cw[j] = wp[j]; }

    // 16 byte-counters packed in two u64s (no runtime-indexed arrays -> no scratch)
    unsigned long long h0 = 0, h1 = 0;
#pragma unroll
    for (int j = 0; j < K; ++j) {
        const int key = ci[j] & 15;
        const unsigned long long one = 1ull << ((key & 7) << 3);
        if (key < 8) h0 += one; else h1 += one;
    }
    // exclusive prefix sum -> packed start offsets (counts <= 32 fit a byte)
    unsigned long long o0 = 0, o1 = 0;
    {
        unsigned run = 0;
#pragma unroll
        for (int kk = 0; kk < 8; ++kk) {
            o0 |= (unsigned long long)run << (kk << 3);
            run += (unsigned)((h0 >> (kk << 3)) & 0xffull);
        }
#pragma unroll
        for (int kk = 0; kk < 8; ++kk) {
            o1 |= (unsigned long long)run << (kk << 3);
            run += (unsigned)((h1 >> (kk << 3)) & 0xffull);
        }
    }
    // place (stable within key), rotated by lane; bijective j -> slot
#pragma unroll
    for (int j = 0; j < K; ++j) {
        const int key = ci[j] & 15;
        const int sh  = (key & 7) << 3;
        int pos;
        if (key < 8) { pos = (int)((o0 >> sh) & 0xff); o0 += 1ull << sh; }
        else         { pos = (int)((o1 >> sh) & 0xff); o1 += 1ull << sh; }
        const int slot = (pos + rot) & 31;
        io[slot] = (unsigned short)ci[j];
        wo[slot] = (_Float16)cw[j];
    }
}

// ---- gather-dot building block: 8 gathers, packed fp16 accumulate
// (2x v_pk_fma_f16 per gather instead of 4 cvt + 4 fma), folded into f32.
// Group partial sums span <= 8 products of magnitude ~0.2 -> fp16 rounding
// ~6e-4 pre-activation, same order as the fp16 storage quantization.
#define GROUP8(CI, W8, ACC)                                                   \
    {                                                                         \
        hv2 aL = {(_Float16)0.f, (_Float16)0.f};                              \
        hv2 aH = {(_Float16)0.f, (_Float16)0.f};                              \
        _Pragma("unroll")                                                     \
        for (int j = 0; j < 8; ++j) {                                         \
            const int c = (int)(CI)[j];                                       \
            const hh  v = buf[c];                                             \
            hv2 wt2; wt2.x = (W8)[j]; wt2.y = (W8)[j];                        \
            aL = __builtin_elementwise_fma(v.lo, wt2, aL);                    \
            aH = __builtin_elementwise_fma(v.hi, wt2, aH);                    \
        }                                                                     \
        ACC.x += (float)aL.x;  ACC.y += (float)aL.y;                          \
        ACC.z += (float)aH.x;  ACC.w += (float)aH.y;                          \
    }

#define LAYER(IDXQ, LI)                                                       \
    {                                                                         \
        const h8* wp = (const h8*)(wh + ((size_t)(LI) * N + t) * K);          \
        const h8 w0 = wp[0], w1 = wp[1], w2 = wp[2], w3 = wp[3];              \
        float4 acc = make_float4(0.f, 0.f, 0.f, 0.f);                         \
        GROUP8(IDXQ[0], w0, acc)                                              \
        GROUP8(IDXQ[1], w1, acc)                                              \
        GROUP8(IDXQ[2], w2, acc)                                              \
        GROUP8(IDXQ[3], w3, acc)                                              \
        const float bb = bias[(LI) * N + t];                                  \
        hh o;                                                                 \
        o.lo.x = (_Float16)sigmoidf_fast(acc.x + bb);                         \
        o.lo.y = (_Float16)sigmoidf_fast(acc.y + bb);                         \
        o.hi.x = (_Float16)sigmoidf_fast(acc.z + bb);                         \
        o.hi.y = (_Float16)sigmoidf_fast(acc.w + bb);                         \
        buf[NIN + (LI) * N + t] = o;                                          \
    }

// buf[c] = {row0..row3} fp16 (8 B). 68 KB -> 2 blocks/CU.
// Per layer per thread: 4x dwordx4 idx (ping-pong prefetched one layer
// ahead) + 4x dwordx4 W + 32 ds_read_b64 gathers (bank-balanced) +
// 64 v_pk_fma_f16 + 16 cvt + 16 add fold.
__global__ __launch_bounds__(BLOCK, 4)
void ffnet_kernel(const float* __restrict__ x,
                  const float* __restrict__ bias,
                  const float* __restrict__ bias_out,
                  const _Float16*       __restrict__ wh,
                  const unsigned short* __restrict__ i16,
                  const _Float16*       __restrict__ who,
                  const unsigned short* __restrict__ io16,
                  float* __restrict__ out)
{
    __shared__ hh buf[TOTAL];   // 68 KB

    const int t  = threadIdx.x;
    const int r0 = blockIdx.x * BROWS;

    // ---- stage x (transposed): thread t owns column t (NIN == BLOCK)
    {
        hh v;
        v.lo.x = (_Float16)x[(size_t)(r0 + 0) * NIN + t];
        v.lo.y = (_Float16)x[(size_t)(r0 + 1) * NIN + t];
        v.hi.x = (_Float16)x[(size_t)(r0 + 2) * NIN + t];
        v.hi.y = (_Float16)x[(size_t)(r0 + 3) * NIN + t];
        buf[t] = v;
    }

    // ---- prefetch layer 0 indices (latency overlaps the barrier)
    u16x8 ia[4], ib[4];
    {
        const u16x8* ip = (const u16x8*)(i16 + (size_t)t * K);
        ia[0] = ip[0]; ia[1] = ip[1]; ia[2] = ip[2]; ia[3] = ip[3];
    }
    __syncthreads();

    // ---- 16 hidden layers, ping-pong index register sets (no copies).
    // Writes go past all reads of the current layer: one barrier per layer.
    for (int l = 0; l < L; l += 2) {
        {   // prefetch odd layer's indices — lands during even layer's math
            const u16x8* np = (const u16x8*)(i16 + ((size_t)(l + 1) * N + t) * K);
            ib[0] = np[0]; ib[1] = np[1]; ib[2] = np[2]; ib[3] = np[3];
        }
        LAYER(ia, l)
        __syncthreads();

        if (l + 2 < L) {   // prefetch next even layer
            const u16x8* np = (const u16x8*)(i16 + ((size_t)(l + 2) * N + t) * K);
            ia[0] = np[0]; ia[1] = np[1]; ia[2] = np[2]; ia[3] = np[3];
        } else if (t < NOUT) {   // last iteration: prefetch output indices
            const u16x8* np = (const u16x8*)(io16 + (size_t)t * K);
            ia[0] = np[0]; ia[1] = np[1]; ia[2] = np[2]; ia[3] = np[3];
        }
        LAYER(ib, l + 1)
        __syncthreads();
    }

    // ---- output layer: threads 0..NOUT-1 (indices already in ia)
    if (t < NOUT) {
        const h8* wp = (const h8*)(who + (size_t)t * K);
        const h8 w0 = wp[0], w1 = wp[1], w2 = wp[2], w3 = wp[3];

        float4 acc = make_float4(0.f, 0.f, 0.f, 0.f);
        GROUP8(ia[0], w0, acc)
        GROUP8(ia[1], w1, acc)
        GROUP8(ia[2], w2, acc)
        GROUP8(ia[3], w3, acc)

        const float bb = bias_out[t];
        out[(size_t)(r0 + 0) * NOUT + t] = sigmoidf_fast(acc.x + bb);
        out[(size_t)(r0 + 1) * NOUT + t] = sigmoidf_fast(acc.y + bb);
        out[(size_t)(r0 + 2) * NOUT + t] = sigmoidf_fast(acc.z + bb);
        out[(size_t)(r0 + 3) * NOUT + t] = sigmoidf_fast(acc.w + bb);
    }
}

extern "C" void kernel_launch(void* const* d_in, const int* in_sizes, int n_in,
                              void* d_out, int out_size, void* d_ws, size_t ws_size,
                              hipStream_t stream) {
    const float* x     = (const float*)d_in[0];   // (B, NIN)
    const float* W     = (const float*)d_in[1];   // (L, N, K)
    const float* b     = (const float*)d_in[2];   // (L, N)
    const float* W_out = (const float*)d_in[3];   // (NOUT, K)
    const float* b_out = (const float*)d_in[4];   // (NOUT,)
    const int*   idx   = (const int*)d_in[5];     // (L, N, K)
    const int*   idx_o = (const int*)d_in[6];     // (NOUT, K)
    float* out = (float*)d_out;                   // (B, NOUT)

    // workspace layout — IDENTICAL footprint to the proven 1.08 MB baseline
    char* ws = (char*)d_ws;
    _Float16*       wh   = (_Float16*)      (ws);                         // 512 KB
    unsigned short* i16  = (unsigned short*)(ws + 524288);                // 512 KB
    _Float16*       who  = (_Float16*)      (ws + 1048576);               // 16 KB
    unsigned short* io16 = (unsigned short*)(ws + 1048576 + 16384);       // 16 KB

    const int nneur = HID + NOUT;                 // 8448
    repack_kernel<<<dim3((nneur + 255) / 256), dim3(256), 0, stream>>>(
        W, idx, W_out, idx_o, wh, i16, who, io16);

    ffnet_kernel<<<dim3(B / BROWS), dim3(BLOCK), 0, stream>>>(
        x, b, b_out, wh, i16, who, io16, out);
}

// Round 3
// 146.986 us; speedup vs baseline: 1.1185x; 1.1185x over previous
//
#include <hip/hip_runtime.h>
#include <hip/hip_fp16.h>
#include <math.h>

// Problem dims (fixed)
#define B     4096
#define NIN   512
#define L     16
#define N     512
#define K     32
#define NOUT  256
#define HID   (L * N)          // 8192
#define TOTAL (NIN + L * N)    // 8704
#define BROWS 4                // batch rows per block
#define BLOCK 512              // one neuron per thread per layer

typedef __attribute__((ext_vector_type(2))) _Float16 hv2;         // 4 B: 2 fp16
typedef __attribute__((ext_vector_type(8))) _Float16 h8;          // 16 B: 8 packed fp16 weights
typedef __attribute__((ext_vector_type(8))) unsigned short u16x8; // 16 B: 8 packed u16 offsets

// 8 B LDS entry: 4 batch rows of one column as two fp16 pairs
struct alignas(8) hh { hv2 lo, hi; };

__device__ __forceinline__ float sigmoidf_fast(float z) {
    return 1.0f / (1.0f + __expf(-z));
}

// ---- repack with LATIN-TEMPLATE bank scheduling (drift-free, unlike the
// round-2 sort+rotate which let multinomial count-drift misalign lanes):
//  * item with bank-pair key k = idx & 15, within-key rank r < 2 goes to
//    slot ((k - rot) & 15) + 16 r,  rot = neuron & 15.  At gather slot j the
//    32 lanes of a phase then read each bank-pair EXACTLY twice (= the HW
//    floor, zero excess) wherever counts allow. Surplus items (E~8/32)
//    spill into leftover slots — local deviations only, no cumulative drift.
//  * hidden-layer offsets stored PRE-SCALED (idx*8 <= 65528 fits u16):
//    ds_read vaddr = loaded halfword, zero shift VALU. Output-layer idx
//    (< 8704) stays unscaled; ffnet shifts by 3 there (256 threads only).
//  Dot product is permutation-invariant -> numerically free.
//  Footprint identical to the proven 1.08 MB workspace layout.
__global__ void repack_kernel(const float* __restrict__ W,
                              const int*   __restrict__ idx,
                              const float* __restrict__ W_out,
                              const int*   __restrict__ idx_out,
                              _Float16* __restrict__ wh,
                              unsigned short* __restrict__ i16,
                              _Float16* __restrict__ who,
                              unsigned short* __restrict__ io16)
{
    const int n = blockIdx.x * 64 + threadIdx.x;
    const int* ip; const float* wp; _Float16* wo; unsigned short* io; int scale;
    if (n < HID) {
        ip = idx + (size_t)n * K;      wp = W + (size_t)n * K;
        wo = wh + (size_t)n * K;       io = i16 + (size_t)n * K;   scale = 3;
    } else if (n < HID + NOUT) {
        const int m = n - HID;
        ip = idx_out + (size_t)m * K;  wp = W_out + (size_t)m * K;
        wo = who + (size_t)m * K;      io = io16 + (size_t)m * K;  scale = 0;
    } else {
        return;
    }
    const int rot = n & 15;

    int ci[K]; float cw[K];
#pragma unroll
    for (int j = 0; j < K; ++j) { ci[j] = ip[j]; cw[j] = wp[j]; }

    // rank within key via two u64 packed byte counters (no runtime-indexed
    // arrays -> stays in registers)
    unsigned long long r0 = 0, r1 = 0;
    int sl[K];
    unsigned used = 0;
#pragma unroll
    for (int j = 0; j < K; ++j) {
        const int key = ci[j] & 15;
        const int sh  = (key & 7) << 3;
        int rank;
        if (key < 8) { rank = (int)((r0 >> sh) & 0xff); r0 += 1ull << sh; }
        else         { rank = (int)((r1 >> sh) & 0xff); r1 += 1ull << sh; }
        if (rank < 2) {           // template slot: unique per (key, rank)
            const int s = ((key - rot) & 15) + (rank << 4);
            sl[j] = s; used |= 1u << s;
        } else {
            sl[j] = -1;           // surplus -> spill pass
        }
    }
#pragma unroll
    for (int j = 0; j < K; ++j) {
        int s = sl[j];
        if (s < 0) { s = (int)__builtin_ctz(~used); used |= 1u << s; }
        io[s] = (unsigned short)(ci[j] << scale);
        wo[s] = (_Float16)cw[j];
    }
}

// ---- gather-dot building block: 8 gathers, packed fp16 accumulate
// (2x v_pk_fma_f16 per gather), folded into f32 every 8 (group rounding
// ~6e-4 pre-activation — same order as fp16 storage quantization).
// SH = 0 for hidden layers (offsets pre-scaled), 3 for the output layer.
#define GROUP8(CI, W8, SH, ACC)                                               \
    {                                                                         \
        hv2 aL = {(_Float16)0.f, (_Float16)0.f};                              \
        hv2 aH = {(_Float16)0.f, (_Float16)0.f};                              \
        _Pragma("unroll")                                                     \
        for (int j = 0; j < 8; ++j) {                                         \
            const int c = ((int)(CI)[j]) << (SH);                             \
            const hh  v = *(const hh*)((const char*)buf + c);                 \
            hv2 wt2; wt2.x = (W8)[j]; wt2.y = (W8)[j];                        \
            aL = __builtin_elementwise_fma(v.lo, wt2, aL);                    \
            aH = __builtin_elementwise_fma(v.hi, wt2, aH);                    \
        }                                                                     \
        ACC.x += (float)aL.x;  ACC.y += (float)aL.y;                          \
        ACC.z += (float)aH.x;  ACC.w += (float)aH.y;                          \
    }

#define LAYER(IDXQ, LI)                                                       \
    {                                                                         \
        const h8* wp = (const h8*)(wh + ((size_t)(LI) * N + t) * K);          \
        const h8 w0 = wp[0], w1 = wp[1], w2 = wp[2], w3 = wp[3];              \
        float4 acc = make_float4(0.f, 0.f, 0.f, 0.f);                         \
        GROUP8(IDXQ[0], w0, 0, acc)                                           \
        GROUP8(IDXQ[1], w1, 0, acc)                                           \
        GROUP8(IDXQ[2], w2, 0, acc)                                           \
        GROUP8(IDXQ[3], w3, 0, acc)                                           \
        const float bb = bias[(LI) * N + t];                                  \
        hh o;                                                                 \
        o.lo.x = (_Float16)sigmoidf_fast(acc.x + bb);                         \
        o.lo.y = (_Float16)sigmoidf_fast(acc.y + bb);                         \
        o.hi.x = (_Float16)sigmoidf_fast(acc.z + bb);                         \
        o.hi.y = (_Float16)sigmoidf_fast(acc.w + bb);                         \
        buf[NIN + (LI) * N + t] = o;                                          \
    }

// buf[c] = {row0..row3} fp16 (8 B). 68 KB -> 2 blocks/CU.
// Per layer per thread: 4x dwordx4 idx (ping-pong prefetched one layer
// ahead) + 4x dwordx4 W + 32 ds_read_b64 gathers (Latin-template banked,
// vaddr = pre-scaled halfword) + 64 v_pk_fma_f16 + fold + sigmoid.
__global__ __launch_bounds__(BLOCK, 4)
void ffnet_kernel(const float* __restrict__ x,
                  const float* __restrict__ bias,
                  const float* __restrict__ bias_out,
                  const _Float16*       __restrict__ wh,
                  const unsigned short* __restrict__ i16,
                  const _Float16*       __restrict__ who,
                  const unsigned short* __restrict__ io16,
                  float* __restrict__ out)
{
    __shared__ hh buf[TOTAL];   // 68 KB, LDS offset 0 -> vaddr = offset

    const int t  = threadIdx.x;
    const int r0 = blockIdx.x * BROWS;

    // ---- stage x (transposed): thread t owns column t (NIN == BLOCK)
    {
        hh v;
        v.lo.x = (_Float16)x[(size_t)(r0 + 0) * NIN + t];
        v.lo.y = (_Float16)x[(size_t)(r0 + 1) * NIN + t];
        v.hi.x = (_Float16)x[(size_t)(r0 + 2) * NIN + t];
        v.hi.y = (_Float16)x[(size_t)(r0 + 3) * NIN + t];
        buf[t] = v;
    }

    // ---- prefetch layer 0 offsets (latency overlaps the barrier)
    u16x8 ia[4], ib[4];
    {
        const u16x8* ip = (const u16x8*)(i16 + (size_t)t * K);
        ia[0] = ip[0]; ia[1] = ip[1]; ia[2] = ip[2]; ia[3] = ip[3];
    }
    __syncthreads();

    // ---- 16 hidden layers, ping-pong index register sets (no copies).
    // Writes go past all reads of the current layer: one barrier per layer.
    for (int l = 0; l < L; l += 2) {
        {   // prefetch odd layer's offsets — lands during even layer's math
            const u16x8* np = (const u16x8*)(i16 + ((size_t)(l + 1) * N + t) * K);
            ib[0] = np[0]; ib[1] = np[1]; ib[2] = np[2]; ib[3] = np[3];
        }
        LAYER(ia, l)
        __syncthreads();

        if (l + 2 < L) {   // prefetch next even layer
            const u16x8* np = (const u16x8*)(i16 + ((size_t)(l + 2) * N + t) * K);
            ia[0] = np[0]; ia[1] = np[1]; ia[2] = np[2]; ia[3] = np[3];
        } else if (t < NOUT) {   // last iteration: prefetch output offsets
            const u16x8* np = (const u16x8*)(io16 + (size_t)t * K);
            ia[0] = np[0]; ia[1] = np[1]; ia[2] = np[2]; ia[3] = np[3];
        }
        LAYER(ib, l + 1)
        __syncthreads();
    }

    // ---- output layer: threads 0..NOUT-1 (offsets already in ia, unscaled)
    if (t < NOUT) {
        const h8* wp = (const h8*)(who + (size_t)t * K);
        const h8 w0 = wp[0], w1 = wp[1], w2 = wp[2], w3 = wp[3];

        float4 acc = make_float4(0.f, 0.f, 0.f, 0.f);
        GROUP8(ia[0], w0, 3, acc)
        GROUP8(ia[1], w1, 3, acc)
        GROUP8(ia[2], w2, 3, acc)
        GROUP8(ia[3], w3, 3, acc)

        const float bb = bias_out[t];
        out[(size_t)(r0 + 0) * NOUT + t] = sigmoidf_fast(acc.x + bb);
        out[(size_t)(r0 + 1) * NOUT + t] = sigmoidf_fast(acc.y + bb);
        out[(size_t)(r0 + 2) * NOUT + t] = sigmoidf_fast(acc.z + bb);
        out[(size_t)(r0 + 3) * NOUT + t] = sigmoidf_fast(acc.w + bb);
    }
}

extern "C" void kernel_launch(void* const* d_in, const int* in_sizes, int n_in,
                              void* d_out, int out_size, void* d_ws, size_t ws_size,
                              hipStream_t stream) {
    const float* x     = (const float*)d_in[0];   // (B, NIN)
    const float* W     = (const float*)d_in[1];   // (L, N, K)
    const float* b     = (const float*)d_in[2];   // (L, N)
    const float* W_out = (const float*)d_in[3];   // (NOUT, K)
    const float* b_out = (const float*)d_in[4];   // (NOUT,)
    const int*   idx   = (const int*)d_in[5];     // (L, N, K)
    const int*   idx_o = (const int*)d_in[6];     // (NOUT, K)
    float* out = (float*)d_out;                   // (B, NOUT)

    // workspace layout — IDENTICAL footprint to the proven 1.08 MB baseline
    char* ws = (char*)d_ws;
    _Float16*       wh   = (_Float16*)      (ws);                         // 512 KB
    unsigned short* i16  = (unsigned short*)(ws + 524288);                // 512 KB
    _Float16*       who  = (_Float16*)      (ws + 1048576);               // 16 KB
    unsigned short* io16 = (unsigned short*)(ws + 1048576 + 16384);       // 16 KB

    const int nneur = HID + NOUT;                 // 8448
    repack_kernel<<<dim3((nneur + 63) / 64), dim3(64), 0, stream>>>(
        W, idx, W_out, idx_o, wh, i16, who, io16);

    ffnet_kernel<<<dim3(B / BROWS), dim3(BLOCK), 0, stream>>>(
        x, b, b_out, wh, i16, who, io16, out);
}

// Round 5
// 145.219 us; speedup vs baseline: 1.1321x; 1.0122x over previous
//
#include <hip/hip_runtime.h>
#include <hip/hip_fp16.h>
#include <math.h>

// Problem dims (fixed)
#define B     4096
#define NIN   512
#define L     16
#define N     512
#define K     32
#define NOUT  256
#define HID   (L * N)          // 8192
#define TOTAL (NIN + L * N)    // 8704
#define BROWS 4                // batch rows per block
#define BLOCK 512              // one neuron per thread per layer

typedef __attribute__((ext_vector_type(2))) _Float16 hv2;         // 4 B: 2 fp16
typedef __attribute__((ext_vector_type(8))) _Float16 h8;          // 16 B: 8 packed fp16 weights
typedef __attribute__((ext_vector_type(8))) unsigned short u16x8; // 16 B: 8 packed u16 offsets

// 8 B LDS entry: 4 batch rows of one column as two fp16 pairs
struct alignas(8) hh { hv2 lo, hi; };

__device__ __forceinline__ float sigmoidf_fast(float z) {
    return 1.0f / (1.0f + __expf(-z));
}

// ---- repack with LATIN-TEMPLATE bank scheduling (round-3 winner logic;
// loads vectorized int4/float4):
//  * item with bank-pair key k = idx & 15, rank r < 2 -> slot ((k-rot)&15)+16r,
//    rot = neuron & 15: at each gather slot a 16-lane phase reads each
//    bank-pair exactly once where counts allow (HW floor). Surplus items
//    (E~8/32) spill into leftover holes — the measured residual conflicts.
//  * hidden-layer offsets PRE-SCALED (idx*8 <= 65528 fits u16): ds_read
//    vaddr = loaded halfword. Output idx (< 8704) unscaled, shifted by 3.
//  Dot product is permutation-invariant -> numerically free.
__global__ void repack_kernel(const float* __restrict__ W,
                              const int*   __restrict__ idx,
                              const float* __restrict__ W_out,
                              const int*   __restrict__ idx_out,
                              _Float16* __restrict__ wh,
                              unsigned short* __restrict__ i16,
                              _Float16* __restrict__ who,
                              unsigned short* __restrict__ io16)
{
    const int n = blockIdx.x * 64 + threadIdx.x;
    const int* ip; const float* wp; _Float16* wo; unsigned short* io; int scale;
    if (n < HID) {
        ip = idx + (size_t)n * K;      wp = W + (size_t)n * K;
        wo = wh + (size_t)n * K;       io = i16 + (size_t)n * K;   scale = 3;
    } else if (n < HID + NOUT) {
        const int m = n - HID;
        ip = idx_out + (size_t)m * K;  wp = W_out + (size_t)m * K;
        wo = who + (size_t)m * K;      io = io16 + (size_t)m * K;  scale = 0;
    } else {
        return;
    }
    const int rot = n & 15;

    // vectorized loads (rows are 128 B aligned)
    int ci[K]; float cw[K];
    {
        const int4*   ip4 = (const int4*)ip;
        const float4* wp4 = (const float4*)wp;
#pragma unroll
        for (int q = 0; q < 8; ++q) {
            const int4   a = ip4[q];
            const float4 f = wp4[q];
            ci[q * 4 + 0] = a.x; ci[q * 4 + 1] = a.y;
            ci[q * 4 + 2] = a.z; ci[q * 4 + 3] = a.w;
            cw[q * 4 + 0] = f.x; cw[q * 4 + 1] = f.y;
            cw[q * 4 + 2] = f.z; cw[q * 4 + 3] = f.w;
        }
    }

    // rank within key via two u64 packed byte counters (register-resident)
    unsigned long long r0 = 0, r1 = 0;
    int sl[K];
    unsigned used = 0;
#pragma unroll
    for (int j = 0; j < K; ++j) {
        const int key = ci[j] & 15;
        const int sh  = (key & 7) << 3;
        int rank;
        if (key < 8) { rank = (int)((r0 >> sh) & 0xff); r0 += 1ull << sh; }
        else         { rank = (int)((r1 >> sh) & 0xff); r1 += 1ull << sh; }
        if (rank < 2) {           // template slot: unique per (key, rank)
            const int s = ((key - rot) & 15) + (rank << 4);
            sl[j] = s; used |= 1u << s;
        } else {
            sl[j] = -1;           // surplus -> spill pass
        }
    }
#pragma unroll
    for (int j = 0; j < K; ++j) {
        int s = sl[j];
        if (s < 0) { s = (int)__builtin_ctz(~used); used |= 1u << s; }
        io[s] = (unsigned short)(ci[j] << scale);
        wo[s] = (_Float16)cw[j];
    }
}

// ---- issue a batch of 8 gathers into a register array (no FMA dependency:
// lets the compiler keep many ds_reads in flight under fine-grained lgkmcnt)
#define GATHERS(CI, V, SH)                                                    \
    _Pragma("unroll")                                                         \
    for (int j = 0; j < 8; ++j) {                                             \
        const int c = ((int)(CI)[j]) << (SH);                                 \
        (V)[j] = *(const hh*)((const char*)buf + c);                          \
    }

// ---- 8-element packed-fp16 FMA batch folded into f32 (group rounding
// ~6e-4 pre-activation — same order as fp16 storage quantization)
#define FMA8(V, W8, ACC)                                                      \
    {                                                                         \
        hv2 aL = {(_Float16)0.f, (_Float16)0.f};                              \
        hv2 aH = {(_Float16)0.f, (_Float16)0.f};                              \
        _Pragma("unroll")                                                     \
        for (int j = 0; j < 8; ++j) {                                         \
            hv2 wt2; wt2.x = (W8)[j]; wt2.y = (W8)[j];                        \
            aL = __builtin_elementwise_fma((V)[j].lo, wt2, aL);               \
            aH = __builtin_elementwise_fma((V)[j].hi, wt2, aH);               \
        }                                                                     \
        (ACC).x += (float)aL.x;  (ACC).y += (float)aL.y;                      \
        (ACC).z += (float)aH.x;  (ACC).w += (float)aH.y;                      \
    }

// Software-pipelined layer: weights issued first (L2 latency overlaps gather
// issue), 24 gathers in flight before the first FMA, 4th batch issued
// between FMA groups. Peak live regs ~110 (launch bounds cap 128).
#define LAYER(IDXQ, LI)                                                       \
    {                                                                         \
        const h8* wp = (const h8*)(wh + ((size_t)(LI) * N + t) * K);          \
        const h8 w0 = wp[0], w1 = wp[1], w2 = wp[2], w3 = wp[3];              \
        const float bb = bias[(LI) * N + t];                                  \
        hh v0[8], v1[8], v2[8], v3[8];                                        \
        GATHERS(IDXQ[0], v0, 0)                                               \
        GATHERS(IDXQ[1], v1, 0)                                               \
        GATHERS(IDXQ[2], v2, 0)                                               \
        float4 acc = make_float4(0.f, 0.f, 0.f, 0.f);                         \
        FMA8(v0, w0, acc)                                                     \
        GATHERS(IDXQ[3], v3, 0)                                               \
        FMA8(v1, w1, acc)                                                     \
        FMA8(v2, w2, acc)                                                     \
        FMA8(v3, w3, acc)                                                     \
        hh o;                                                                 \
        o.lo.x = (_Float16)sigmoidf_fast(acc.x + bb);                         \
        o.lo.y = (_Float16)sigmoidf_fast(acc.y + bb);                         \
        o.hi.x = (_Float16)sigmoidf_fast(acc.z + bb);                         \
        o.hi.y = (_Float16)sigmoidf_fast(acc.w + bb);                         \
        buf[NIN + (LI) * N + t] = o;                                          \
    }

// buf[c] = {row0..row3} fp16 (8 B). 68 KB -> 2 blocks/CU.
__global__ __launch_bounds__(BLOCK, 4)
void ffnet_kernel(const float* __restrict__ x,
                  const float* __restrict__ bias,
                  const float* __restrict__ bias_out,
                  const _Float16*       __restrict__ wh,
                  const unsigned short* __restrict__ i16,
                  const _Float16*       __restrict__ who,
                  const unsigned short* __restrict__ io16,
                  float* __restrict__ out)
{
    __shared__ hh buf[TOTAL];   // 68 KB, LDS offset 0 -> vaddr = offset

    const int t  = threadIdx.x;
    const int r0 = blockIdx.x * BROWS;

    // ---- stage x (transposed): thread t owns column t (NIN == BLOCK)
    {
        hh v;
        v.lo.x = (_Float16)x[(size_t)(r0 + 0) * NIN + t];
        v.lo.y = (_Float16)x[(size_t)(r0 + 1) * NIN + t];
        v.hi.x = (_Float16)x[(size_t)(r0 + 2) * NIN + t];
        v.hi.y = (_Float16)x[(size_t)(r0 + 3) * NIN + t];
        buf[t] = v;
    }

    // ---- prefetch layer 0 offsets (latency overlaps the barrier)
    u16x8 ia[4], ib[4];
    {
        const u16x8* ip = (const u16x8*)(i16 + (size_t)t * K);
        ia[0] = ip[0]; ia[1] = ip[1]; ia[2] = ip[2]; ia[3] = ip[3];
    }
    __syncthreads();

    // ---- 16 hidden layers, ping-pong index register sets.
    // Writes go past all reads of the current layer: one barrier per layer.
    for (int l = 0; l < L; l += 2) {
        {   // prefetch odd layer's offsets — lands during even layer's math
            const u16x8* np = (const u16x8*)(i16 + ((size_t)(l + 1) * N + t) * K);
            ib[0] = np[0]; ib[1] = np[1]; ib[2] = np[2]; ib[3] = np[3];
        }
        LAYER(ia, l)
        __syncthreads();

        if (l + 2 < L) {   // prefetch next even layer
            const u16x8* np = (const u16x8*)(i16 + ((size_t)(l + 2) * N + t) * K);
            ia[0] = np[0]; ia[1] = np[1]; ia[2] = np[2]; ia[3] = np[3];
        } else if (t < NOUT) {   // last iteration: prefetch output offsets
            const u16x8* np = (const u16x8*)(io16 + (size_t)t * K);
            ia[0] = np[0]; ia[1] = np[1]; ia[2] = np[2]; ia[3] = np[3];
        }
        LAYER(ib, l + 1)
        __syncthreads();
    }

    // ---- output layer: threads 0..NOUT-1 (offsets already in ia, unscaled)
    if (t < NOUT) {
        const h8* wp = (const h8*)(who + (size_t)t * K);
        const h8 w0 = wp[0], w1 = wp[1], w2 = wp[2], w3 = wp[3];
        const float bb = bias_out[t];

        hh v0[8], v1[8], v2[8], v3[8];
        GATHERS(ia[0], v0, 3)
        GATHERS(ia[1], v1, 3)
        GATHERS(ia[2], v2, 3)
        float4 acc = make_float4(0.f, 0.f, 0.f, 0.f);
        FMA8(v0, w0, acc)
        GATHERS(ia[3], v3, 3)
        FMA8(v1, w1, acc)
        FMA8(v2, w2, acc)
        FMA8(v3, w3, acc)

        out[(size_t)(r0 + 0) * NOUT + t] = sigmoidf_fast(acc.x + bb);
        out[(size_t)(r0 + 1) * NOUT + t] = sigmoidf_fast(acc.y + bb);
        out[(size_t)(r0 + 2) * NOUT + t] = sigmoidf_fast(acc.z + bb);
        out[(size_t)(r0 + 3) * NOUT + t] = sigmoidf_fast(acc.w + bb);
    }
}

extern "C" void kernel_launch(void* const* d_in, const int* in_sizes, int n_in,
                              void* d_out, int out_size, void* d_ws, size_t ws_size,
                              hipStream_t stream) {
    const float* x     = (const float*)d_in[0];   // (B, NIN)
    const float* W     = (const float*)d_in[1];   // (L, N, K)
    const float* b     = (const float*)d_in[2];   // (L, N)
    const float* W_out = (const float*)d_in[3];   // (NOUT, K)
    const float* b_out = (const float*)d_in[4];   // (NOUT,)
    const int*   idx   = (const int*)d_in[5];     // (L, N, K)
    const int*   idx_o = (const int*)d_in[6];     // (NOUT, K)
    float* out = (float*)d_out;                   // (B, NOUT)

    // workspace layout — IDENTICAL footprint to the proven 1.08 MB baseline
    char* ws = (char*)d_ws;
    _Float16*       wh   = (_Float16*)      (ws);                         // 512 KB
    unsigned short* i16  = (unsigned short*)(ws + 524288);                // 512 KB
    _Float16*       who  = (_Float16*)      (ws + 1048576);               // 16 KB
    unsigned short* io16 = (unsigned short*)(ws + 1048576 + 16384);       // 16 KB

    const int nneur = HID + NOUT;                 // 8448
    repack_kernel<<<dim3((nneur + 63) / 64), dim3(64), 0, stream>>>(
        W, idx, W_out, idx_o, wh, i16, who, io16);

    ffnet_kernel<<<dim3(B / BROWS), dim3(BLOCK), 0, stream>>>(
        x, b, b_out, wh, i16, who, io16, out);
}